// Round 10
// baseline (64.711 us; speedup 1.0000x reference)
//
#include <hip/hip_runtime.h>
#include <hip/hip_bf16.h>

#define B_ 2048
#define D_ 17
#define H_ 8
#define HID_ 256
#define OUT_ 23
#define XROW 8721       /* 513*17 floats per batch */

__device__ __forceinline__ float4 ld4u(const float* p) {   // 4B-aligned 16B load
  float4 v; __builtin_memcpy(&v, p, 16); return v;
}
__device__ __forceinline__ float bclane(float v, int l) {  // wave broadcast via readlane
  return __uint_as_float(__builtin_amdgcn_readlane(__float_as_uint(v), l));
}

// ---------------- Kernel 1: prep — transpose W2s + fold q into Wk ----------------
__global__ __launch_bounds__(256) void prep_kernel(
    const float* __restrict__ pW2, const float* __restrict__ vW2,
    const float* __restrict__ Wk, const float* __restrict__ bk,
    const float* __restrict__ q,
    float* __restrict__ pW2t, float* __restrict__ vW2t, float* __restrict__ qkc)
{
  const int bid = blockIdx.x;
  const int t = threadIdx.x;
  if (bid == 128) {
    if (t < H_ * D_) {
      const int h = t / D_, dd = t - h * D_;
      float s = 0.f;
      #pragma unroll
      for (int e = 0; e < D_; ++e) s = fmaf(Wk[h*289 + e*D_ + dd], q[h*D_ + e], s);
      qkc[h*18 + dd] = s;
    } else if (t < H_ * D_ + H_) {
      const int h = t - H_ * D_;
      float s = 0.f;
      #pragma unroll
      for (int e = 0; e < D_; ++e) s = fmaf(bk[h*D_ + e], q[h*D_ + e], s);
      qkc[h*18 + 17] = s;
    }
    return;
  }
  __shared__ float tile[32][33];
  const int m = bid >> 6, tid = bid & 63;
  const int ti = (tid >> 3) * 32, tk = (tid & 7) * 32;
  const float* src = m ? vW2 : pW2;
  float* dst = m ? vW2t : pW2t;
  const int tx = t & 31, ty = t >> 5;
  #pragma unroll
  for (int r = 0; r < 4; ++r) tile[ty + 8*r][tx] = src[(ti + ty + 8*r)*HID_ + tk + tx];
  __syncthreads();
  #pragma unroll
  for (int r = 0; r < 4; ++r) dst[(tk + ty + 8*r)*HID_ + ti + tx] = tile[tx][ty + 8*r];
}

// ---------------- Kernel 2: attention partials, 4 independent waves / batch ----------------
// Grid 2048 x 256 thr = 4 waves, NO LDS, NO barriers. Wave w takes chunks {w, w+4, ...}
// (chunk = 8 rows) -> balanced work; monotone mask per wave; speculative depth-2 stream,
// break on first all-dead ballot. lane = (head=l&7, rowgroup=l>>3); lanes 0-7 write
// (den, acc[17]) per head to part[(b*4+w)*144 + h*18].
__global__ __launch_bounds__(256, 6) void attn_part_kernel(
    const float* __restrict__ x, const float* __restrict__ qkc,
    float* __restrict__ part)
{
  const int b = blockIdx.x;
  const int t = threadIdx.x;
  const int w = t >> 6, lane = t & 63;
  const int h = lane & 7, rg = lane >> 3;
  const float* xs = x + (size_t)b * XROW + D_;

  float qk[D_];
  #pragma unroll
  for (int d = 0; d < D_; ++d) qk[d] = qkc[h*18 + d];
  const float chr = qkc[h*18 + 17];

  float den = 0.f, acc[D_];
  #pragma unroll
  for (int d = 0; d < D_; ++d) acc[d] = 0.f;

  const float* rb = xs + (size_t)rg * D_;
  float4 A0, A1, A2, A3; float A4;
  float4 C0, C1, C2, C3; float C4;
  auto loadA = [&](int c) {
    const float* rp = rb + c * 136;
    A0 = ld4u(rp); A1 = ld4u(rp+4); A2 = ld4u(rp+8); A3 = ld4u(rp+12); A4 = rp[16];
  };
  auto loadC = [&](int c) {
    const float* rp = rb + c * 136;
    C0 = ld4u(rp); C1 = ld4u(rp+4); C2 = ld4u(rp+8); C3 = ld4u(rp+12); C4 = rp[16];
  };
  auto comp = [&](const float4& v0, const float4& v1, const float4& v2, const float4& v3, float v4) {
    float sc = chr;
    sc = fmaf(qk[0],  v0.x, sc); sc = fmaf(qk[1],  v0.y, sc);
    sc = fmaf(qk[2],  v0.z, sc); sc = fmaf(qk[3],  v0.w, sc);
    sc = fmaf(qk[4],  v1.x, sc); sc = fmaf(qk[5],  v1.y, sc);
    sc = fmaf(qk[6],  v1.z, sc); sc = fmaf(qk[7],  v1.w, sc);
    sc = fmaf(qk[8],  v2.x, sc); sc = fmaf(qk[9],  v2.y, sc);
    sc = fmaf(qk[10], v2.z, sc); sc = fmaf(qk[11], v2.w, sc);
    sc = fmaf(qk[12], v3.x, sc); sc = fmaf(qk[13], v3.y, sc);
    sc = fmaf(qk[14], v3.z, sc); sc = fmaf(qk[15], v3.w, sc);
    sc = fmaf(qk[16], v4, sc);
    const float p = (v0.x != 0.f) ? __expf(sc) : 0.f;   // per-row mask (masked rows exact zeros)
    den += p;
    acc[0]  = fmaf(p, v0.x, acc[0]);  acc[1]  = fmaf(p, v0.y, acc[1]);
    acc[2]  = fmaf(p, v0.z, acc[2]);  acc[3]  = fmaf(p, v0.w, acc[3]);
    acc[4]  = fmaf(p, v1.x, acc[4]);  acc[5]  = fmaf(p, v1.y, acc[5]);
    acc[6]  = fmaf(p, v1.z, acc[6]);  acc[7]  = fmaf(p, v1.w, acc[7]);
    acc[8]  = fmaf(p, v2.x, acc[8]);  acc[9]  = fmaf(p, v2.y, acc[9]);
    acc[10] = fmaf(p, v2.z, acc[10]); acc[11] = fmaf(p, v2.w, acc[11]);
    acc[12] = fmaf(p, v3.x, acc[12]); acc[13] = fmaf(p, v3.y, acc[13]);
    acc[14] = fmaf(p, v3.z, acc[14]); acc[15] = fmaf(p, v3.w, acc[15]);
    acc[16] = fmaf(p, v4, acc[16]);
  };

  loadA(w);
  #pragma unroll 1
  for (int c = w; c < 64; c += 8) {          // pair = chunks c, c+4 (stride 4 = wave count)
    if (c + 4 < 64) loadC(c + 4);
    if (__ballot(A0.x != 0.f) == 0ull) break; // chunk all dead -> tail dead (monotone)
    comp(A0, A1, A2, A3, A4);
    if (c + 4 >= 64) break;
    if (c + 8 < 64) loadA(c + 8);
    if (__ballot(C0.x != 0.f) == 0ull) break;
    comp(C0, C1, C2, C3, C4);
  }

  // reduce over rowgroups (same-head lanes are stride-8)
  #pragma unroll
  for (int m = 8; m <= 32; m <<= 1) {
    den += __shfl_xor(den, m, 64);
    #pragma unroll
    for (int d = 0; d < D_; ++d) acc[d] += __shfl_xor(acc[d], m, 64);
  }
  if (lane < 8) {
    float* pp = part + ((size_t)b * 4 + w) * 144 + lane * 18;
    pp[0] = den;
    #pragma unroll
    for (int d = 0; d < D_; ++d) pp[1 + d] = acc[d];
  }
}

// ---------------- Kernel 3: combine + fused policy/value MLPs ----------------
// Grid 256 x 512 thr, 8 batches/block. Prologue: part -> swn -> agg(Wv) -> Wo -> s_comb.
// Then readlane mlp: layer-1 in regs, layer-2 via v_readlane broadcast (no LDS pipe).
__global__ __launch_bounds__(512) void mlp_fused_kernel(
    const float* __restrict__ x, const float* __restrict__ part,
    const float* __restrict__ Wv, const float* __restrict__ bv,
    const float* __restrict__ Wo, const float* __restrict__ bo,
    const float* __restrict__ pW1, const float* __restrict__ pb1,
    const float* __restrict__ pW2t, const float* __restrict__ pb2,
    const float* __restrict__ pW3, const float* __restrict__ pb3,
    const float* __restrict__ vW1, const float* __restrict__ vb1,
    const float* __restrict__ vW2t, const float* __restrict__ vb2,
    const float* __restrict__ vW3, const float* __restrict__ vb3,
    float* __restrict__ out)
{
  __shared__ float s_swn[8][136];
  __shared__ float s_agg[8][136];
  __shared__ float s_wp[8][136];
  __shared__ float s_comb[8][26];
  __shared__ __align__(16) float s_red[2][3][8][HID_];
  __shared__ __align__(16) float s_h2[2][8][HID_];

  const int t = threadIdx.x;
  const int b0 = blockIdx.x * 8;
  const int cb = t >> 6;          // combine-phase batch 0..7
  const int cl = t & 63;

  // ---- combine phase A: swn[h][d] = (sum_w acc) / (sum_w den)
  {
    const float* pb_ = part + (size_t)(b0 + cb) * 4 * 144;
    for (int u = cl; u < 136; u += 64) {
      const int hh = u / D_, d = u - hh * D_;
      const float dn = pb_[hh*18] + pb_[144 + hh*18] + pb_[288 + hh*18] + pb_[432 + hh*18];
      const float ac = pb_[hh*18+1+d] + pb_[144 + hh*18+1+d] + pb_[288 + hh*18+1+d] + pb_[432 + hh*18+1+d];
      s_swn[cb][u] = ac / dn;
    }
  }
  __syncthreads();
  // ---- B: agg = bv + Wv·swn
  for (int u = cl; u < 136; u += 64) {
    const int hh = u / D_, e = u - hh * D_;
    float s = bv[u];
    #pragma unroll
    for (int d = 0; d < D_; ++d) s = fmaf(Wv[hh*289 + e*D_ + d], s_swn[cb][hh*D_ + d], s);
    s_agg[cb][u] = s;
  }
  __syncthreads();
  // ---- C: Wo partials (17 outs x 8 k-parts)
  for (int u = cl; u < 136; u += 64) {
    const int o = u >> 3, pt = u & 7;
    float s = 0.f;
    #pragma unroll
    for (int j = 0; j < D_; ++j) s = fmaf(Wo[o*136 + pt*D_ + j], s_agg[cb][pt*D_ + j], s);
    s_wp[cb][u] = s;
  }
  __syncthreads();
  // ---- D: comb = [attn(17) | special(9)]
  if (cl < D_) {
    float s = bo[cl];
    #pragma unroll
    for (int pt = 0; pt < 8; ++pt) s += s_wp[cb][cl*8 + pt];
    s_comb[cb][cl] = s;
  } else if (cl < 26) {
    s_comb[cb][cl] = x[(size_t)(b0 + cb) * XROW + (cl - D_)];
  }
  __syncthreads();

  // ---- MLPs: t = p(1)|kq(2)|ln(6)
  const int p = t >> 8;
  const int kq = (t >> 6) & 3;
  const int ln = t & 63;
  const float* W1  = p ? vW1  : pW1;   const float* B1 = p ? vb1 : pb1;
  const float* W2t = p ? vW2t : pW2t;  const float* B2 = p ? vb2 : pb2;

  // layer 1: output i = kq*64+ln for 8 batches, kept in registers
  float h[8];
  {
    const int i = kq * 64 + ln;
    float a[8];
    #pragma unroll
    for (int bb = 0; bb < 8; ++bb) a[bb] = 0.f;
    const float* wr = W1 + i * 26;
    for (int k = 0; k < 26; ++k) {
      const float wk = wr[k];
      #pragma unroll
      for (int bb = 0; bb < 8; ++bb) a[bb] = fmaf(wk, s_comb[bb][k], a[bb]);
    }
    const float bias = B1[i];
    #pragma unroll
    for (int bb = 0; bb < 8; ++bb) h[bb] = fmaxf(a[bb] + bias, 0.f);
  }

  // layer 2: k-slice [kq*64, +64); h1[bb][kq*64+jj] lives in lane jj of THIS wave
  float4 acc[8];
  #pragma unroll
  for (int bb = 0; bb < 8; ++bb) acc[bb] = make_float4(0.f, 0.f, 0.f, 0.f);
  {
    const float* wbase = W2t + (size_t)(kq * 64) * HID_ + 4 * ln;
    #pragma unroll 8
    for (int jj = 0; jj < 64; ++jj) {
      const float4 wv = *(const float4*)(wbase + (size_t)jj * HID_);
      #pragma unroll
      for (int bb = 0; bb < 8; ++bb) {
        const float hv = bclane(h[bb], jj);
        acc[bb].x = fmaf(wv.x, hv, acc[bb].x);
        acc[bb].y = fmaf(wv.y, hv, acc[bb].y);
        acc[bb].z = fmaf(wv.z, hv, acc[bb].z);
        acc[bb].w = fmaf(wv.w, hv, acc[bb].w);
      }
    }
  }
  if (kq > 0) {
    #pragma unroll
    for (int bb = 0; bb < 8; ++bb) *(float4*)&s_red[p][kq - 1][bb][4 * ln] = acc[bb];
  }
  __syncthreads();
  if (kq == 0) {
    const float4 bias = *(const float4*)&B2[4 * ln];
    #pragma unroll
    for (int bb = 0; bb < 8; ++bb) {
      const float4 r0 = *(const float4*)&s_red[p][0][bb][4 * ln];
      const float4 r1 = *(const float4*)&s_red[p][1][bb][4 * ln];
      const float4 r2 = *(const float4*)&s_red[p][2][bb][4 * ln];
      float4 r;
      r.x = fmaxf(acc[bb].x + r0.x + r1.x + r2.x + bias.x, 0.f);
      r.y = fmaxf(acc[bb].y + r0.y + r1.y + r2.y + bias.y, 0.f);
      r.z = fmaxf(acc[bb].z + r0.z + r1.z + r2.z + bias.z, 0.f);
      r.w = fmaxf(acc[bb].w + r0.w + r1.w + r2.w + bias.w, 0.f);
      *(float4*)&s_h2[p][bb][4 * ln] = r;
    }
  }
  __syncthreads();

  // layer 3
  if (t < 184) {                        // policy: 8 batches x 23 outputs
    const int bb = t / OUT_, o = t - bb * OUT_;
    const float4* w4 = (const float4*)(pW3 + o * HID_);
    const float4* h4 = (const float4*)&s_h2[0][bb][0];
    float s = pb3[o];
    for (int k = 0; k < 64; ++k) {
      const float4 wv = w4[k], hv = h4[k];
      s = fmaf(wv.x, hv.x, fmaf(wv.y, hv.y, fmaf(wv.z, hv.z, fmaf(wv.w, hv.w, s))));
    }
    out[(size_t)(b0 + bb) * OUT_ + o] = s;
  } else if (t >= 256 && t < 264) {     // value: 8 batches x 1 output
    const int bb = t - 256;
    const float4* w4 = (const float4*)vW3;
    const float4* h4 = (const float4*)&s_h2[1][bb][0];
    float s = vb3[0];
    for (int k = 0; k < 64; ++k) {
      const float4 wv = w4[k], hv = h4[k];
      s = fmaf(wv.x, hv.x, fmaf(wv.y, hv.y, fmaf(wv.z, hv.z, fmaf(wv.w, hv.w, s))));
    }
    out[(size_t)B_ * OUT_ + b0 + bb] = s;
  }
}

extern "C" void kernel_launch(void* const* d_in, const int* in_sizes, int n_in,
                              void* d_out, int out_size, void* d_ws, size_t ws_size,
                              hipStream_t stream) {
  (void)in_sizes; (void)n_in; (void)out_size; (void)ws_size;
  const float* x   = (const float*)d_in[0];
  const float* Wk  = (const float*)d_in[1];
  const float* bk  = (const float*)d_in[2];
  const float* Wv  = (const float*)d_in[3];
  const float* bv  = (const float*)d_in[4];
  const float* q   = (const float*)d_in[5];
  const float* Wo  = (const float*)d_in[6];
  const float* bo  = (const float*)d_in[7];
  const float* pW1 = (const float*)d_in[8];
  const float* pb1 = (const float*)d_in[9];
  const float* pW2 = (const float*)d_in[10];
  const float* pb2 = (const float*)d_in[11];
  const float* pW3 = (const float*)d_in[12];
  const float* pb3 = (const float*)d_in[13];
  const float* vW1 = (const float*)d_in[14];
  const float* vb1 = (const float*)d_in[15];
  const float* vW2 = (const float*)d_in[16];
  const float* vb2 = (const float*)d_in[17];
  const float* vW3 = (const float*)d_in[18];
  const float* vb3 = (const float*)d_in[19];
  float* out = (float*)d_out;

  // workspace: pW2t (65536) | vW2t (65536) | qkc (144+pad) | part (2048*4*144) floats
  float* pW2t = (float*)d_ws;
  float* vW2t = pW2t + (size_t)HID_ * HID_;
  float* qkc  = vW2t + (size_t)HID_ * HID_;
  float* part = qkc + 160;

  prep_kernel<<<129, 256, 0, stream>>>(pW2, vW2, Wk, bk, q, pW2t, vW2t, qkc);
  attn_part_kernel<<<B_, 256, 0, stream>>>(x, qkc, part);
  mlp_fused_kernel<<<B_ / 8, 512, 0, stream>>>(x, part, Wv, bv, Wo, bo,
                                               pW1, pb1, pW2t, pb2, pW3, pb3,
                                               vW1, vb1, vW2t, vb2, vW3, vb3, out);
}

// Round 11
// 63.522 us; speedup vs baseline: 1.0187x; 1.0187x over previous
//
#include <hip/hip_runtime.h>
#include <hip/hip_bf16.h>

#define B_ 2048
#define D_ 17
#define H_ 8
#define HID_ 256
#define OUT_ 23
#define XROW 8721       /* 513*17 floats per batch */

__device__ __forceinline__ float4 ld4u(const float* p) {   // 4B-aligned 16B load
  float4 v; __builtin_memcpy(&v, p, 16); return v;
}
__device__ __forceinline__ float bclane(float v, int l) {  // wave broadcast via readlane
  return __uint_as_float(__builtin_amdgcn_readlane(__float_as_uint(v), l));
}

// ---------------- Kernel 1: prep — transpose W2s + fold q into Wk ----------------
__global__ __launch_bounds__(256) void prep_kernel(
    const float* __restrict__ pW2, const float* __restrict__ vW2,
    const float* __restrict__ Wk, const float* __restrict__ bk,
    const float* __restrict__ q,
    float* __restrict__ pW2t, float* __restrict__ vW2t, float* __restrict__ qkc)
{
  const int bid = blockIdx.x;
  const int t = threadIdx.x;
  if (bid == 128) {
    if (t < H_ * D_) {
      const int h = t / D_, dd = t - h * D_;
      float s = 0.f;
      #pragma unroll
      for (int e = 0; e < D_; ++e) s = fmaf(Wk[h*289 + e*D_ + dd], q[h*D_ + e], s);
      qkc[h*18 + dd] = s;
    } else if (t < H_ * D_ + H_) {
      const int h = t - H_ * D_;
      float s = 0.f;
      #pragma unroll
      for (int e = 0; e < D_; ++e) s = fmaf(bk[h*D_ + e], q[h*D_ + e], s);
      qkc[h*18 + 17] = s;
    }
    return;
  }
  __shared__ float tile[32][33];
  const int m = bid >> 6, tid = bid & 63;
  const int ti = (tid >> 3) * 32, tk = (tid & 7) * 32;
  const float* src = m ? vW2 : pW2;
  float* dst = m ? vW2t : pW2t;
  const int tx = t & 31, ty = t >> 5;
  #pragma unroll
  for (int r = 0; r < 4; ++r) tile[ty + 8*r][tx] = src[(ti + ty + 8*r)*HID_ + tk + tx];
  __syncthreads();
  #pragma unroll
  for (int r = 0; r < 4; ++r) dst[(tk + ty + 8*r)*HID_ + ti + tx] = tile[tx][ty + 8*r];
}

// ---------------- Kernel 2: attention partials — 1 row/lane-quad, head-pairs ----------------
// Grid 1024 x 256 thr = 4 waves; wave = (batch = bi*2 + (w>>1), half = w&1) -> 256 rows.
// lane = (hp = lane>>4 owns heads {2hp,2hp+1}, r = lane&15). Phase = 16 rows: 5 load
// instrs/lane (own row; 4 same-row lanes dedup), 70 FMA/lane. Ping-pong prefetch,
// ballot early-exit (monotone mask). 4-round shfl reduce over the 16-lane row group.
__global__ __launch_bounds__(256, 4) void attn_part_kernel(
    const float* __restrict__ x, const float* __restrict__ qkc,
    float* __restrict__ part)
{
  const int t = threadIdx.x;
  const int w = t >> 6, lane = t & 63;
  const int hp = lane >> 4;           // head-pair: heads 2hp, 2hp+1
  const int r  = lane & 15;           // row within phase
  const int b    = blockIdx.x * 2 + (w >> 1);
  const int half = w & 1;

  const float* xs = x + (size_t)b * XROW + D_ + (size_t)(half << 8) * D_;
  const float* rb = xs + (size_t)r * D_;          // row r of phase 0; phase stride 272 floats

  // qk for this lane's two heads (wave-uniform per hp group)
  const float* q0 = qkc + (2*hp) * 18;
  const float* q1 = q0 + 18;
  float qk0[D_], qk1[D_];
  #pragma unroll
  for (int d = 0; d < D_; ++d) { qk0[d] = q0[d]; qk1[d] = q1[d]; }
  const float ch0 = q0[17], ch1 = q1[17];

  float den0 = 0.f, den1 = 0.f;
  float acc0[D_], acc1[D_];
  #pragma unroll
  for (int d = 0; d < D_; ++d) { acc0[d] = 0.f; acc1[d] = 0.f; }

  float A[D_], C[D_];
  auto loadA = [&](int ph) {
    const float* rp = rb + ph * 272;
    const float4 v0 = ld4u(rp), v1 = ld4u(rp+4), v2 = ld4u(rp+8), v3 = ld4u(rp+12);
    A[0]=v0.x; A[1]=v0.y; A[2]=v0.z; A[3]=v0.w;
    A[4]=v1.x; A[5]=v1.y; A[6]=v1.z; A[7]=v1.w;
    A[8]=v2.x; A[9]=v2.y; A[10]=v2.z; A[11]=v2.w;
    A[12]=v3.x; A[13]=v3.y; A[14]=v3.z; A[15]=v3.w;
    A[16]=rp[16];
  };
  auto loadC = [&](int ph) {
    const float* rp = rb + ph * 272;
    const float4 v0 = ld4u(rp), v1 = ld4u(rp+4), v2 = ld4u(rp+8), v3 = ld4u(rp+12);
    C[0]=v0.x; C[1]=v0.y; C[2]=v0.z; C[3]=v0.w;
    C[4]=v1.x; C[5]=v1.y; C[6]=v1.z; C[7]=v1.w;
    C[8]=v2.x; C[9]=v2.y; C[10]=v2.z; C[11]=v2.w;
    C[12]=v3.x; C[13]=v3.y; C[14]=v3.z; C[15]=v3.w;
    C[16]=rp[16];
  };
  auto comp = [&](const float* f) {
    float s0 = ch0, s1 = ch1;
    #pragma unroll
    for (int d = 0; d < D_; ++d) { s0 = fmaf(qk0[d], f[d], s0); s1 = fmaf(qk1[d], f[d], s1); }
    const bool live = (f[0] != 0.f);   // masked rows exact zeros; live word0==0 P~1e-45
    const float p0 = live ? __expf(s0) : 0.f;
    const float p1 = live ? __expf(s1) : 0.f;
    den0 += p0; den1 += p1;
    #pragma unroll
    for (int d = 0; d < D_; ++d) {
      acc0[d] = fmaf(p0, f[d], acc0[d]);
      acc1[d] = fmaf(p1, f[d], acc1[d]);
    }
  };

  loadA(0);
  #pragma unroll 1
  for (int ph = 0; ph < 16; ph += 2) {
    if (ph + 1 < 16) loadC(ph + 1);
    if (__ballot(A[0] != 0.f) == 0ull) break;   // 16 rows all dead -> tail dead
    comp(A);
    if (ph + 1 >= 16) break;
    if (ph + 2 < 16) loadA(ph + 2);
    if (__ballot(C[0] != 0.f) == 0ull) break;
    comp(C);
  }

  // reduce over the 16 row-lanes within each hp group
  #pragma unroll
  for (int m = 1; m <= 8; m <<= 1) {
    den0 += __shfl_xor(den0, m, 64);
    den1 += __shfl_xor(den1, m, 64);
    #pragma unroll
    for (int d = 0; d < D_; ++d) {
      acc0[d] += __shfl_xor(acc0[d], m, 64);
      acc1[d] += __shfl_xor(acc1[d], m, 64);
    }
  }
  if (r == 0) {
    float* pp = part + ((size_t)b * 2 + half) * 144 + (2*hp) * 18;
    pp[0] = den0; pp[18] = den1;
    #pragma unroll
    for (int d = 0; d < D_; ++d) { pp[1 + d] = acc0[d]; pp[19 + d] = acc1[d]; }
  }
}

// ---------------- Kernel 3: combine + fused policy/value MLPs ----------------
// Grid 256 x 512 thr, 8 batches/block. Prologue: part(2 halves) -> swn -> agg(Wv) -> Wo
// -> s_comb. Then readlane mlp: layer-1 in regs, layer-2 via v_readlane (no LDS pipe).
__global__ __launch_bounds__(512) void mlp_fused_kernel(
    const float* __restrict__ x, const float* __restrict__ part,
    const float* __restrict__ Wv, const float* __restrict__ bv,
    const float* __restrict__ Wo, const float* __restrict__ bo,
    const float* __restrict__ pW1, const float* __restrict__ pb1,
    const float* __restrict__ pW2t, const float* __restrict__ pb2,
    const float* __restrict__ pW3, const float* __restrict__ pb3,
    const float* __restrict__ vW1, const float* __restrict__ vb1,
    const float* __restrict__ vW2t, const float* __restrict__ vb2,
    const float* __restrict__ vW3, const float* __restrict__ vb3,
    float* __restrict__ out)
{
  __shared__ float s_swn[8][136];
  __shared__ float s_agg[8][136];
  __shared__ float s_wp[8][136];
  __shared__ float s_comb[8][26];
  __shared__ __align__(16) float s_red[2][3][8][HID_];
  __shared__ __align__(16) float s_h2[2][8][HID_];

  const int t = threadIdx.x;
  const int b0 = blockIdx.x * 8;
  const int cb = t >> 6;          // combine-phase batch 0..7
  const int cl = t & 63;

  // ---- combine A: swn[h][d] = (sum over 2 halves acc) / (sum den)
  {
    const float* pb_ = part + (size_t)(b0 + cb) * 288;
    for (int u = cl; u < 136; u += 64) {
      const int hh = u / D_, d = u - hh * D_;
      const float dn = pb_[hh*18] + pb_[144 + hh*18];
      const float ac = pb_[hh*18 + 1 + d] + pb_[144 + hh*18 + 1 + d];
      s_swn[cb][u] = ac / dn;
    }
  }
  __syncthreads();
  // ---- B: agg = bv + Wv·swn
  for (int u = cl; u < 136; u += 64) {
    const int hh = u / D_, e = u - hh * D_;
    float s = bv[u];
    #pragma unroll
    for (int d = 0; d < D_; ++d) s = fmaf(Wv[hh*289 + e*D_ + d], s_swn[cb][hh*D_ + d], s);
    s_agg[cb][u] = s;
  }
  __syncthreads();
  // ---- C: Wo partials (17 outs x 8 k-parts)
  for (int u = cl; u < 136; u += 64) {
    const int o = u >> 3, pt = u & 7;
    float s = 0.f;
    #pragma unroll
    for (int j = 0; j < D_; ++j) s = fmaf(Wo[o*136 + pt*D_ + j], s_agg[cb][pt*D_ + j], s);
    s_wp[cb][u] = s;
  }
  __syncthreads();
  // ---- D: comb = [attn(17) | special(9)]
  if (cl < D_) {
    float s = bo[cl];
    #pragma unroll
    for (int pt = 0; pt < 8; ++pt) s += s_wp[cb][cl*8 + pt];
    s_comb[cb][cl] = s;
  } else if (cl < 26) {
    s_comb[cb][cl] = x[(size_t)(b0 + cb) * XROW + (cl - D_)];
  }
  __syncthreads();

  // ---- MLPs: t = p(1)|kq(2)|ln(6)
  const int p = t >> 8;
  const int kq = (t >> 6) & 3;
  const int ln = t & 63;
  const float* W1  = p ? vW1  : pW1;   const float* B1 = p ? vb1 : pb1;
  const float* W2t = p ? vW2t : pW2t;  const float* B2 = p ? vb2 : pb2;

  // layer 1: output i = kq*64+ln for 8 batches, kept in registers
  float h[8];
  {
    const int i = kq * 64 + ln;
    float a[8];
    #pragma unroll
    for (int bb = 0; bb < 8; ++bb) a[bb] = 0.f;
    const float* wr = W1 + i * 26;
    for (int k = 0; k < 26; ++k) {
      const float wk = wr[k];
      #pragma unroll
      for (int bb = 0; bb < 8; ++bb) a[bb] = fmaf(wk, s_comb[bb][k], a[bb]);
    }
    const float bias = B1[i];
    #pragma unroll
    for (int bb = 0; bb < 8; ++bb) h[bb] = fmaxf(a[bb] + bias, 0.f);
  }

  // layer 2: k-slice [kq*64, +64); h1[bb][kq*64+jj] lives in lane jj of THIS wave
  float4 acc[8];
  #pragma unroll
  for (int bb = 0; bb < 8; ++bb) acc[bb] = make_float4(0.f, 0.f, 0.f, 0.f);
  {
    const float* wbase = W2t + (size_t)(kq * 64) * HID_ + 4 * ln;
    #pragma unroll 8
    for (int jj = 0; jj < 64; ++jj) {
      const float4 wv = *(const float4*)(wbase + (size_t)jj * HID_);
      #pragma unroll
      for (int bb = 0; bb < 8; ++bb) {
        const float hv = bclane(h[bb], jj);
        acc[bb].x = fmaf(wv.x, hv, acc[bb].x);
        acc[bb].y = fmaf(wv.y, hv, acc[bb].y);
        acc[bb].z = fmaf(wv.z, hv, acc[bb].z);
        acc[bb].w = fmaf(wv.w, hv, acc[bb].w);
      }
    }
  }
  if (kq > 0) {
    #pragma unroll
    for (int bb = 0; bb < 8; ++bb) *(float4*)&s_red[p][kq - 1][bb][4 * ln] = acc[bb];
  }
  __syncthreads();
  if (kq == 0) {
    const float4 bias = *(const float4*)&B2[4 * ln];
    #pragma unroll
    for (int bb = 0; bb < 8; ++bb) {
      const float4 r0 = *(const float4*)&s_red[p][0][bb][4 * ln];
      const float4 r1 = *(const float4*)&s_red[p][1][bb][4 * ln];
      const float4 r2 = *(const float4*)&s_red[p][2][bb][4 * ln];
      float4 rr;
      rr.x = fmaxf(acc[bb].x + r0.x + r1.x + r2.x + bias.x, 0.f);
      rr.y = fmaxf(acc[bb].y + r0.y + r1.y + r2.y + bias.y, 0.f);
      rr.z = fmaxf(acc[bb].z + r0.z + r1.z + r2.z + bias.z, 0.f);
      rr.w = fmaxf(acc[bb].w + r0.w + r1.w + r2.w + bias.w, 0.f);
      *(float4*)&s_h2[p][bb][4 * ln] = rr;
    }
  }
  __syncthreads();

  // layer 3
  if (t < 184) {                        // policy: 8 batches x 23 outputs
    const int bb = t / OUT_, o = t - bb * OUT_;
    const float4* w4 = (const float4*)(pW3 + o * HID_);
    const float4* h4 = (const float4*)&s_h2[0][bb][0];
    float s = pb3[o];
    for (int k = 0; k < 64; ++k) {
      const float4 wv = w4[k], hv = h4[k];
      s = fmaf(wv.x, hv.x, fmaf(wv.y, hv.y, fmaf(wv.z, hv.z, fmaf(wv.w, hv.w, s))));
    }
    out[(size_t)(b0 + bb) * OUT_ + o] = s;
  } else if (t >= 256 && t < 264) {     // value: 8 batches x 1 output
    const int bb = t - 256;
    const float4* w4 = (const float4*)vW3;
    const float4* h4 = (const float4*)&s_h2[1][bb][0];
    float s = vb3[0];
    for (int k = 0; k < 64; ++k) {
      const float4 wv = w4[k], hv = h4[k];
      s = fmaf(wv.x, hv.x, fmaf(wv.y, hv.y, fmaf(wv.z, hv.z, fmaf(wv.w, hv.w, s))));
    }
    out[(size_t)B_ * OUT_ + b0 + bb] = s;
  }
}

extern "C" void kernel_launch(void* const* d_in, const int* in_sizes, int n_in,
                              void* d_out, int out_size, void* d_ws, size_t ws_size,
                              hipStream_t stream) {
  (void)in_sizes; (void)n_in; (void)out_size; (void)ws_size;
  const float* x   = (const float*)d_in[0];
  const float* Wk  = (const float*)d_in[1];
  const float* bk  = (const float*)d_in[2];
  const float* Wv  = (const float*)d_in[3];
  const float* bv  = (const float*)d_in[4];
  const float* q   = (const float*)d_in[5];
  const float* Wo  = (const float*)d_in[6];
  const float* bo  = (const float*)d_in[7];
  const float* pW1 = (const float*)d_in[8];
  const float* pb1 = (const float*)d_in[9];
  const float* pW2 = (const float*)d_in[10];
  const float* pb2 = (const float*)d_in[11];
  const float* pW3 = (const float*)d_in[12];
  const float* pb3 = (const float*)d_in[13];
  const float* vW1 = (const float*)d_in[14];
  const float* vb1 = (const float*)d_in[15];
  const float* vW2 = (const float*)d_in[16];
  const float* vb2 = (const float*)d_in[17];
  const float* vW3 = (const float*)d_in[18];
  const float* vb3 = (const float*)d_in[19];
  float* out = (float*)d_out;

  // workspace: pW2t (65536) | vW2t (65536) | qkc (160) | part (2048*2*144) floats
  float* pW2t = (float*)d_ws;
  float* vW2t = pW2t + (size_t)HID_ * HID_;
  float* qkc  = vW2t + (size_t)HID_ * HID_;
  float* part = qkc + 160;

  prep_kernel<<<129, 256, 0, stream>>>(pW2, vW2, Wk, bk, q, pW2t, vW2t, qkc);
  attn_part_kernel<<<B_ / 2, 256, 0, stream>>>(x, qkc, part);
  mlp_fused_kernel<<<B_ / 8, 512, 0, stream>>>(x, part, Wv, bv, Wo, bo,
                                               pW1, pb1, pW2t, pb2, pW3, pb3,
                                               vW1, vb1, vW2t, vb2, vW3, vb3, out);
}

// Round 12
// 54.611 us; speedup vs baseline: 1.1849x; 1.1632x over previous
//
#include <hip/hip_runtime.h>
#include <hip/hip_bf16.h>

#define B_ 2048
#define D_ 17
#define H_ 8
#define HID_ 256
#define OUT_ 23
#define XROW 8721       /* 513*17 floats per batch */
#define SEQN 8704       /* 512*17 seq floats per batch */

__device__ __forceinline__ float4 ld4u(const float* p) {   // 4B-aligned 16B load
  float4 v; __builtin_memcpy(&v, p, 16); return v;
}
__device__ __forceinline__ float bclane(float v, int l) {  // wave broadcast via readlane
  return __uint_as_float(__builtin_amdgcn_readlane(__float_as_uint(v), l));
}

// ---------------- Kernel 1: prep — transpose W2s + fold q into Wk ----------------
__global__ __launch_bounds__(256) void prep_kernel(
    const float* __restrict__ pW2, const float* __restrict__ vW2,
    const float* __restrict__ Wk, const float* __restrict__ bk,
    const float* __restrict__ q,
    float* __restrict__ pW2t, float* __restrict__ vW2t, float* __restrict__ qkc)
{
  const int bid = blockIdx.x;
  const int t = threadIdx.x;
  if (bid == 128) {
    if (t < H_ * D_) {
      const int h = t / D_, dd = t - h * D_;
      float s = 0.f;
      #pragma unroll
      for (int e = 0; e < D_; ++e) s = fmaf(Wk[h*289 + e*D_ + dd], q[h*D_ + e], s);
      qkc[h*18 + dd] = s;
    } else if (t < H_ * D_ + H_) {
      const int h = t - H_ * D_;
      float s = 0.f;
      #pragma unroll
      for (int e = 0; e < D_; ++e) s = fmaf(bk[h*D_ + e], q[h*D_ + e], s);
      qkc[h*18 + 17] = s;
    }
    return;
  }
  __shared__ float tile[32][33];
  const int m = bid >> 6, tid = bid & 63;
  const int ti = (tid >> 3) * 32, tk = (tid & 7) * 32;
  const float* src = m ? vW2 : pW2;
  float* dst = m ? vW2t : pW2t;
  const int tx = t & 31, ty = t >> 5;
  #pragma unroll
  for (int r = 0; r < 4; ++r) tile[ty + 8*r][tx] = src[(ti + ty + 8*r)*HID_ + tk + tx];
  __syncthreads();
  #pragma unroll
  for (int r = 0; r < 4; ++r) dst[(tk + ty + 8*r)*HID_ + ti + tx] = tile[tx][ty + 8*r];
}

// ---------------- Kernel 2: coalesced-staged attention -> comb (B x 26) ----------------
// 1 batch/block, 256 thr = 4 waves. Probe length; stage live rows with FILL-PATTERN
// coalesced loads (round = 256 thr x float4 = 4 KB contiguous, all rounds issued
// back-to-back); compute: lane = (hp = lane>>4 owns heads {2hp,2hp+1}, rg = lane&15),
// granule (4 rows) per lane, 4 same-address lanes broadcast; finish comb in-kernel.
__global__ __launch_bounds__(256, 3) void attn_comb_kernel(
    const float* __restrict__ x, const float* __restrict__ qkc,
    const float* __restrict__ Wv, const float* __restrict__ bv,
    const float* __restrict__ Wo, const float* __restrict__ bo,
    float* __restrict__ comb)
{
  __shared__ __align__(16) float s_seq[SEQN];
  __shared__ float s_part[4][H_][18];
  __shared__ float s_swn[136];
  __shared__ float s_agg[136];
  __shared__ float s_wp[136];

  const int t = threadIdx.x;
  const int b = blockIdx.x;
  const int w = t >> 6, lane = t & 63;
  const int hp = lane >> 4;          // head pair: heads 2hp, 2hp+1
  const int rg = lane & 15;          // granule slot within wave
  const float* xb = x + (size_t)b * XROW;
  const float* xs = xb + D_;

  // ---- probe: word0 of rows 8*lane (masked rows exact zeros; live word0==0 P~1e-45)
  const float pv = xs[(size_t)lane * 136];
  const unsigned long long live = __ballot(pv != 0.f) | 1ull;
  const int nrows = 8 * (64 - __builtin_clzll(live));    // multiple of 8, len <= nrows <= len+7

  // ---- bulk stage (fill pattern): issue all live rounds, then write
  {
    const int rounds = (nrows * D_ + 1023) >> 10;        // <= 9
    float4 st[9];
    #pragma unroll
    for (int j = 0; j < 9; ++j) if (j < rounds) {
      int off = ((j << 8) + t) << 2; if (off > SEQN - 4) off = SEQN - 4;
      st[j] = ld4u(xs + off);
    }
    #pragma unroll
    for (int j = 0; j < 9; ++j) if (j < rounds) {
      int off = ((j << 8) + t) << 2; if (off > SEQN - 4) off = SEQN - 4;
      *(float4*)&s_seq[off] = st[j];
    }
  }

  // qk for this lane's two heads (loads overlap staging flight)
  const float* q0 = qkc + (2*hp) * 18;
  float qk0[D_], qk1[D_];
  #pragma unroll
  for (int d = 0; d < D_; ++d) { qk0[d] = q0[d]; qk1[d] = q0[18 + d]; }
  const float ch0 = q0[17], ch1 = q0[35];

  __syncthreads();

  // ---- compute: granule = 4 rows = 68 floats; slot = w*16+rg covers 64 granules/pass
  const int ng = nrows >> 2;                 // live granules (multiple of 2)
  float den0 = 0.f, den1 = 0.f;
  float acc0[D_], acc1[D_];
  #pragma unroll
  for (int d = 0; d < D_; ++d) { acc0[d] = 0.f; acc1[d] = 0.f; }

  auto dorow = [&](const float* f, bool ok) {
    float s0 = ch0, s1 = ch1;
    #pragma unroll
    for (int d = 0; d < D_; ++d) { s0 = fmaf(qk0[d], f[d], s0); s1 = fmaf(qk1[d], f[d], s1); }
    const bool lv = ok && (f[0] != 0.f);
    const float p0 = lv ? __expf(s0) : 0.f;
    const float p1 = lv ? __expf(s1) : 0.f;
    den0 += p0; den1 += p1;
    #pragma unroll
    for (int d = 0; d < D_; ++d) {
      acc0[d] = fmaf(p0, f[d], acc0[d]);
      acc1[d] = fmaf(p1, f[d], acc1[d]);
    }
  };
  auto dogran = [&](int g, bool ok) {
    const float* gb = &s_seq[(ok ? g : 0) * 68];
    {
      float f[36];
      #pragma unroll
      for (int i = 0; i < 9; ++i) {
        const float4 v = *(const float4*)(gb + 4*i);
        f[4*i] = v.x; f[4*i+1] = v.y; f[4*i+2] = v.z; f[4*i+3] = v.w;
      }
      dorow(&f[0], ok); dorow(&f[17], ok);
    }
    {
      float f[36];
      #pragma unroll
      for (int i = 0; i < 9; ++i) {
        const float4 v = *(const float4*)(gb + 32 + 4*i);
        f[4*i] = v.x; f[4*i+1] = v.y; f[4*i+2] = v.z; f[4*i+3] = v.w;
      }
      dorow(&f[2], ok); dorow(&f[19], ok);
    }
  };

  {
    const int g = w * 16 + rg;               // pass 0: granules 0..63 (rows 0..255)
    dogran(g, g < ng);
  }
  if (ng > 64) {                             // pass 1 (block-uniform): granules 64..127
    const int g = w * 16 + rg + 64;
    dogran(g, g < ng);
  }

  // ---- reduce over the 16 consecutive rg lanes of each hp group
  #pragma unroll
  for (int m = 1; m <= 8; m <<= 1) {
    den0 += __shfl_xor(den0, m, 64);
    den1 += __shfl_xor(den1, m, 64);
    #pragma unroll
    for (int d = 0; d < D_; ++d) {
      acc0[d] += __shfl_xor(acc0[d], m, 64);
      acc1[d] += __shfl_xor(acc1[d], m, 64);
    }
  }
  if (rg == 0) {
    float* p0p = &s_part[w][2*hp][0];
    float* p1p = &s_part[w][2*hp + 1][0];
    p0p[0] = den0; p1p[0] = den1;
    #pragma unroll
    for (int d = 0; d < D_; ++d) { p0p[1 + d] = acc0[d]; p1p[1 + d] = acc1[d]; }
  }
  __syncthreads();

  // ---- finish (R6-verified phases)
  if (t < 136) {                        // swn = (sum 4 wave-parts acc) / (sum den)
    const int hh = t / D_, d = t - hh * D_;
    float dn = 0.f, ac = 0.f;
    #pragma unroll
    for (int ww = 0; ww < 4; ++ww) { dn += s_part[ww][hh][0]; ac += s_part[ww][hh][1 + d]; }
    s_swn[t] = ac / dn;
  }
  __syncthreads();
  if (t < 136) {                        // agg = bv + Wv·swn
    const int hh = t / D_, e = t - hh * D_;
    float s = bv[t];
    #pragma unroll
    for (int d = 0; d < D_; ++d) s = fmaf(Wv[hh*289 + e*D_ + d], s_swn[hh*D_ + d], s);
    s_agg[t] = s;
  }
  __syncthreads();
  if (t < 136) {                        // Wo partials: 17 outs x 8 k-parts
    const int o = t >> 3, pt = t & 7;
    float s = 0.f;
    #pragma unroll
    for (int j = 0; j < D_; ++j) s = fmaf(Wo[o*136 + pt*D_ + j], s_agg[pt*D_ + j], s);
    s_wp[t] = s;
  }
  __syncthreads();
  if (t < D_) {
    float s = bo[t];
    #pragma unroll
    for (int pt = 0; pt < 8; ++pt) s += s_wp[t*8 + pt];
    comb[b*26 + t] = s;
  } else if (t < 26) {
    comb[b*26 + t] = xb[t - D_];        // special = x[b, 0, 0..8]
  }
}

// ---------------- Kernel 3: fused policy+value MLPs (readlane layer 2) ----------------
// Grid 256 x 512 thr, 8 batches/block. t = p(1)|kq(2)|ln(6). Layer-1 output i=kq*64+ln
// in registers; layer-2 wave consumes its own k-slice via v_readlane (no LDS pipe).
__global__ __launch_bounds__(512) void mlp_kernel(
    const float* __restrict__ comb,
    const float* __restrict__ pW1, const float* __restrict__ pb1,
    const float* __restrict__ pW2t, const float* __restrict__ pb2,
    const float* __restrict__ pW3, const float* __restrict__ pb3,
    const float* __restrict__ vW1, const float* __restrict__ vb1,
    const float* __restrict__ vW2t, const float* __restrict__ vb2,
    const float* __restrict__ vW3, const float* __restrict__ vb3,
    float* __restrict__ out)
{
  __shared__ float s_comb[8][26];
  __shared__ __align__(16) float s_red[2][3][8][HID_];
  __shared__ __align__(16) float s_h2[2][8][HID_];

  const int t = threadIdx.x;
  const int b0 = blockIdx.x * 8;
  const int p = t >> 8;
  const int kq = (t >> 6) & 3;
  const int ln = t & 63;

  if (t < 208) { const int bb = t / 26, k = t - bb*26; s_comb[bb][k] = comb[(size_t)(b0 + bb)*26 + k]; }
  __syncthreads();

  const float* W1  = p ? vW1  : pW1;   const float* B1 = p ? vb1 : pb1;
  const float* W2t = p ? vW2t : pW2t;  const float* B2 = p ? vb2 : pb2;

  // layer 1: output i = kq*64+ln for 8 batches, kept in registers
  float h[8];
  {
    const int i = kq * 64 + ln;
    float a[8];
    #pragma unroll
    for (int bb = 0; bb < 8; ++bb) a[bb] = 0.f;
    const float* wr = W1 + i * 26;
    for (int k = 0; k < 26; ++k) {
      const float wk = wr[k];
      #pragma unroll
      for (int bb = 0; bb < 8; ++bb) a[bb] = fmaf(wk, s_comb[bb][k], a[bb]);
    }
    const float bias = B1[i];
    #pragma unroll
    for (int bb = 0; bb < 8; ++bb) h[bb] = fmaxf(a[bb] + bias, 0.f);
  }

  // layer 2: k-slice [kq*64, +64); h1[bb][kq*64+jj] lives in lane jj of THIS wave
  float4 acc[8];
  #pragma unroll
  for (int bb = 0; bb < 8; ++bb) acc[bb] = make_float4(0.f, 0.f, 0.f, 0.f);
  {
    const float* wbase = W2t + (size_t)(kq * 64) * HID_ + 4 * ln;
    #pragma unroll 8
    for (int jj = 0; jj < 64; ++jj) {
      const float4 wv = *(const float4*)(wbase + (size_t)jj * HID_);
      #pragma unroll
      for (int bb = 0; bb < 8; ++bb) {
        const float hv = bclane(h[bb], jj);
        acc[bb].x = fmaf(wv.x, hv, acc[bb].x);
        acc[bb].y = fmaf(wv.y, hv, acc[bb].y);
        acc[bb].z = fmaf(wv.z, hv, acc[bb].z);
        acc[bb].w = fmaf(wv.w, hv, acc[bb].w);
      }
    }
  }
  if (kq > 0) {
    #pragma unroll
    for (int bb = 0; bb < 8; ++bb) *(float4*)&s_red[p][kq - 1][bb][4 * ln] = acc[bb];
  }
  __syncthreads();
  if (kq == 0) {
    const float4 bias = *(const float4*)&B2[4 * ln];
    #pragma unroll
    for (int bb = 0; bb < 8; ++bb) {
      const float4 r0 = *(const float4*)&s_red[p][0][bb][4 * ln];
      const float4 r1 = *(const float4*)&s_red[p][1][bb][4 * ln];
      const float4 r2 = *(const float4*)&s_red[p][2][bb][4 * ln];
      float4 rr;
      rr.x = fmaxf(acc[bb].x + r0.x + r1.x + r2.x + bias.x, 0.f);
      rr.y = fmaxf(acc[bb].y + r0.y + r1.y + r2.y + bias.y, 0.f);
      rr.z = fmaxf(acc[bb].z + r0.z + r1.z + r2.z + bias.z, 0.f);
      rr.w = fmaxf(acc[bb].w + r0.w + r1.w + r2.w + bias.w, 0.f);
      *(float4*)&s_h2[p][bb][4 * ln] = rr;
    }
  }
  __syncthreads();

  // layer 3
  if (t < 184) {                        // policy: 8 batches x 23 outputs
    const int bb = t / OUT_, o = t - bb * OUT_;
    const float4* w4 = (const float4*)(pW3 + o * HID_);
    const float4* h4 = (const float4*)&s_h2[0][bb][0];
    float s = pb3[o];
    for (int k = 0; k < 64; ++k) {
      const float4 wv = w4[k], hv = h4[k];
      s = fmaf(wv.x, hv.x, fmaf(wv.y, hv.y, fmaf(wv.z, hv.z, fmaf(wv.w, hv.w, s))));
    }
    out[(size_t)(b0 + bb) * OUT_ + o] = s;
  } else if (t >= 256 && t < 264) {     // value: 8 batches x 1 output
    const int bb = t - 256;
    const float4* w4 = (const float4*)vW3;
    const float4* h4 = (const float4*)&s_h2[1][bb][0];
    float s = vb3[0];
    for (int k = 0; k < 64; ++k) {
      const float4 wv = w4[k], hv = h4[k];
      s = fmaf(wv.x, hv.x, fmaf(wv.y, hv.y, fmaf(wv.z, hv.z, fmaf(wv.w, hv.w, s))));
    }
    out[(size_t)B_ * OUT_ + b0 + bb] = s;
  }
}

extern "C" void kernel_launch(void* const* d_in, const int* in_sizes, int n_in,
                              void* d_out, int out_size, void* d_ws, size_t ws_size,
                              hipStream_t stream) {
  (void)in_sizes; (void)n_in; (void)out_size; (void)ws_size;
  const float* x   = (const float*)d_in[0];
  const float* Wk  = (const float*)d_in[1];
  const float* bk  = (const float*)d_in[2];
  const float* Wv  = (const float*)d_in[3];
  const float* bv  = (const float*)d_in[4];
  const float* q   = (const float*)d_in[5];
  const float* Wo  = (const float*)d_in[6];
  const float* bo  = (const float*)d_in[7];
  const float* pW1 = (const float*)d_in[8];
  const float* pb1 = (const float*)d_in[9];
  const float* pW2 = (const float*)d_in[10];
  const float* pb2 = (const float*)d_in[11];
  const float* pW3 = (const float*)d_in[12];
  const float* pb3 = (const float*)d_in[13];
  const float* vW1 = (const float*)d_in[14];
  const float* vb1 = (const float*)d_in[15];
  const float* vW2 = (const float*)d_in[16];
  const float* vb2 = (const float*)d_in[17];
  const float* vW3 = (const float*)d_in[18];
  const float* vb3 = (const float*)d_in[19];
  float* out = (float*)d_out;

  // workspace: pW2t (65536) | vW2t (65536) | qkc (160) | comb (2048*26) floats
  float* pW2t = (float*)d_ws;
  float* vW2t = pW2t + (size_t)HID_ * HID_;
  float* qkc  = vW2t + (size_t)HID_ * HID_;
  float* comb = qkc + 160;

  prep_kernel<<<129, 256, 0, stream>>>(pW2, vW2, Wk, bk, q, pW2t, vW2t, qkc);
  attn_comb_kernel<<<B_, 256, 0, stream>>>(x, qkc, Wv, bv, Wo, bo, comb);
  mlp_kernel<<<B_ / 8, 512, 0, stream>>>(comb, pW1, pb1, pW2t, pb2, pW3, pb3,
                                         vW1, vb1, vW2t, vb2, vW3, vb3, out);
}